// Round 4
// baseline (983.999 us; speedup 1.0000x reference)
//
#include <hip/hip_runtime.h>
#include <math.h>
#include <stdint.h>

#define ZDIM   512
#define MDIM   512
#define HHN    511
#define NBATCH 65536

typedef float f32x4 __attribute__((ext_vector_type(4)));
typedef short s16x8 __attribute__((ext_vector_type(8)));

// float -> bf16 (round-to-nearest-even), returns low 16 bits
__device__ __forceinline__ uint32_t bf16rne(float x) {
    uint32_t u = __float_as_uint(x);
    return (u + 0x7fffu + ((u >> 16) & 1u)) >> 16;
}
// split x into hi+lo bf16 (x ~= hi + lo, |err| <~ 2^-18 |x|)
__device__ __forceinline__ void split2(float x, short& h, short& l) {
    uint32_t hu = bf16rne(x);
    float hf = __uint_as_float(hu << 16);
    uint32_t lu = bf16rne(x - hf);
    h = (short)hu; l = (short)lu;
}

// ---------------------------------------------------------------------------
// K1: normalize v rows -> vn ; rrii[m] = Rs[m,m] * r2diag[m]
// ---------------------------------------------------------------------------
__global__ void __launch_bounds__(64) prep_kernel(const float* __restrict__ v,
                                                  const float* __restrict__ Rs,
                                                  const float* __restrict__ r2diag,
                                                  float* __restrict__ vn,
                                                  float* __restrict__ rrii) {
    int b    = blockIdx.x;
    int lane = threadIdx.x;  // 64
    if (b < HHN) {
        const float4* src = reinterpret_cast<const float4*>(v + (size_t)b * ZDIM);
        float4 a0 = src[lane * 2];
        float4 a1 = src[lane * 2 + 1];
        float s = a0.x*a0.x + a0.y*a0.y + a0.z*a0.z + a0.w*a0.w
                + a1.x*a1.x + a1.y*a1.y + a1.z*a1.z + a1.w*a1.w;
#pragma unroll
        for (int off = 32; off >= 1; off >>= 1) s += __shfl_xor(s, off, 64);
        float inv = 1.0f / sqrtf(s);
        float4 o0 = make_float4(a0.x*inv, a0.y*inv, a0.z*inv, a0.w*inv);
        float4 o1 = make_float4(a1.x*inv, a1.y*inv, a1.z*inv, a1.w*inv);
        float4* dst = reinterpret_cast<float4*>(vn + (size_t)b * ZDIM);
        dst[lane * 2]     = o0;
        dst[lane * 2 + 1] = o1;
    } else {
        for (int m = lane; m < MDIM; m += 64)
            rrii[m] = Rs[(size_t)m * MDIM + m] * r2diag[m];
    }
}

// ---------------------------------------------------------------------------
// K2: Householder product, 4 rows per wave (4 independent shuffle chains
// interleave -> shuffle latency hidden ~3-4x vs 1 row/wave).
// ---------------------------------------------------------------------------
__global__ void __launch_bounds__(256) householder_kernel(const float* __restrict__ vn,
                                                          float* __restrict__ Q) {
    int wid  = threadIdx.x >> 6;
    int lane = threadIdx.x & 63;
    int wslot = blockIdx.x * 4 + wid;      // 0..127

    float q[4][8];
#pragma unroll
    for (int c = 0; c < 4; ++c)
#pragma unroll
        for (int j = 0; j < 8; ++j) q[c][j] = 0.0f;
#pragma unroll
    for (int c = 0; c < 4; ++c) {
        int r = wslot * 4 + c;
        int base = r - lane * 8;
        if (base >= 0 && base < 8) q[c][base] = 1.0f;
    }

    const float4* vn4 = reinterpret_cast<const float4*>(vn);
    float4 va = vn4[lane * 2];
    float4 vb = vn4[lane * 2 + 1];
    for (int i = 0; i < HHN; ++i) {
        float4 ca = va, cb = vb;
        if (i + 1 < HHN) {
            va = vn4[(size_t)(i + 1) * (ZDIM / 4) + lane * 2];
            vb = vn4[(size_t)(i + 1) * (ZDIM / 4) + lane * 2 + 1];
        }
        float d[4];
#pragma unroll
        for (int c = 0; c < 4; ++c)
            d[c] = q[c][0]*ca.x + q[c][1]*ca.y + q[c][2]*ca.z + q[c][3]*ca.w
                 + q[c][4]*cb.x + q[c][5]*cb.y + q[c][6]*cb.z + q[c][7]*cb.w;
#pragma unroll
        for (int off = 32; off >= 1; off >>= 1) {
#pragma unroll
            for (int c = 0; c < 4; ++c) d[c] += __shfl_xor(d[c], off, 64);
        }
#pragma unroll
        for (int c = 0; c < 4; ++c) {
            float s = -2.0f * d[c];
            q[c][0] = fmaf(s, ca.x, q[c][0]); q[c][1] = fmaf(s, ca.y, q[c][1]);
            q[c][2] = fmaf(s, ca.z, q[c][2]); q[c][3] = fmaf(s, ca.w, q[c][3]);
            q[c][4] = fmaf(s, cb.x, q[c][4]); q[c][5] = fmaf(s, cb.y, q[c][5]);
            q[c][6] = fmaf(s, cb.z, q[c][6]); q[c][7] = fmaf(s, cb.w, q[c][7]);
        }
    }
#pragma unroll
    for (int c = 0; c < 4; ++c) {
        int r = wslot * 4 + c;
        float4* qdst = reinterpret_cast<float4*>(Q + (size_t)r * ZDIM);
        qdst[lane * 2]     = make_float4(q[c][0], q[c][1], q[c][2], q[c][3]);
        qdst[lane * 2 + 1] = make_float4(q[c][4], q[c][5], q[c][6], q[c][7]);
    }
}

// ---------------------------------------------------------------------------
// K3: A = Q @ r1 (natural [z][m]) and B1 = (Q @ r2^T)^T ([m][z]), both as
// split bf16 hi/lo. fp32 accumulate. Masks applied at load.
// ---------------------------------------------------------------------------
__global__ void __launch_bounds__(256) small_gemm_kernel(const float* __restrict__ Q,
                                                         const float* __restrict__ Rs,
                                                         const float* __restrict__ r2diag,
                                                         short* __restrict__ Ah_g,
                                                         short* __restrict__ Al_g,
                                                         short* __restrict__ B1h_g,
                                                         short* __restrict__ B1l_g) {
    int r0 = blockIdx.y * 64;
    int c0 = blockIdx.x * 64;
    int tid = threadIdx.x;
    int tx = tid & 15, ty = tid >> 4;

    __shared__ float Qs[16][68];
    __shared__ float RA[16][68];
    __shared__ float RB[16][68];

    float accA[4][4] = {};
    float accB[4][4] = {};

    for (int k0 = 0; k0 < ZDIM; k0 += 16) {
        {
            int r = tid >> 2, c4 = tid & 3;
            float4 g = *reinterpret_cast<const float4*>(Q + (size_t)(r0 + r) * ZDIM + k0 + c4 * 4);
            Qs[c4*4+0][r] = g.x; Qs[c4*4+1][r] = g.y; Qs[c4*4+2][r] = g.z; Qs[c4*4+3][r] = g.w;
        }
        {
            int kk = tid >> 4, c4 = tid & 15;
            int kg = k0 + kk, cg = c0 + c4 * 4;
            float4 g = *reinterpret_cast<const float4*>(Rs + (size_t)kg * MDIM + cg);
            float4 m;
            m.x = (kg <= cg + 0) ? g.x : 0.0f;
            m.y = (kg <= cg + 1) ? g.y : 0.0f;
            m.z = (kg <= cg + 2) ? g.z : 0.0f;
            m.w = (kg <= cg + 3) ? g.w : 0.0f;
            *reinterpret_cast<float4*>(&RA[kk][c4 * 4]) = m;
        }
        {
            int c = tid >> 2, k4 = tid & 3;
            int cg = c0 + c;
            float4 g = *reinterpret_cast<const float4*>(Rs + (size_t)cg * MDIM + k0 + k4 * 4);
            float gv[4] = {g.x, g.y, g.z, g.w};
#pragma unroll
            for (int qq = 0; qq < 4; ++qq) {
                int kg = k0 + k4 * 4 + qq;
                float val = (kg > cg) ? gv[qq] : ((kg == cg) ? r2diag[cg] : 0.0f);
                RB[k4 * 4 + qq][c] = val;
            }
        }
        __syncthreads();
#pragma unroll
        for (int kk = 0; kk < 16; ++kk) {
            float4 aq = *reinterpret_cast<const float4*>(&Qs[kk][ty * 4]);
            float4 ra = *reinterpret_cast<const float4*>(&RA[kk][tx * 4]);
            float4 rb = *reinterpret_cast<const float4*>(&RB[kk][tx * 4]);
            float av[4]  = {aq.x, aq.y, aq.z, aq.w};
            float rav[4] = {ra.x, ra.y, ra.z, ra.w};
            float rbv[4] = {rb.x, rb.y, rb.z, rb.w};
#pragma unroll
            for (int i = 0; i < 4; ++i)
#pragma unroll
                for (int j = 0; j < 4; ++j) {
                    accA[i][j] = fmaf(av[i], rav[j], accA[i][j]);
                    accB[i][j] = fmaf(av[i], rbv[j], accB[i][j]);
                }
        }
        __syncthreads();
    }
#pragma unroll
    for (int i = 0; i < 4; ++i) {
        int rg = r0 + ty * 4 + i;  // z index
#pragma unroll
        for (int j = 0; j < 4; ++j) {
            int cg = c0 + tx * 4 + j;  // m index
            short h, l;
            split2(accA[i][j], h, l);
            Ah_g[(size_t)rg * MDIM + cg] = h;
            Al_g[(size_t)rg * MDIM + cg] = l;
            split2(accB[i][j], h, l);
            B1h_g[(size_t)cg * ZDIM + rg] = h;
            B1l_g[(size_t)cg * ZDIM + rg] = l;
        }
    }
}

// ---------------------------------------------------------------------------
// K4: gemm1 split-3 MFMA, 128x512 tile, 8 waves (2x4, wave 64x128).
// z staged in double-buffered LDS (hi/lo); B1 fragments read DIRECTLY from
// L2 (1 MB resident) with 1-deep n-pipeline. One barrier per K-step.
// Epilogue: tanh -> packed (hi|lo<<16) into d_out, fused ldj.
// ---------------------------------------------------------------------------
__global__ void __launch_bounds__(512, 2) gemm1_mfma(const float* __restrict__ z,
                                                     const short* __restrict__ B1h,
                                                     const short* __restrict__ B1l,
                                                     const float* __restrict__ cvec,
                                                     const float* __restrict__ rrii,
                                                     uint32_t* __restrict__ hBp,
                                                     float* __restrict__ ldj) {
    int b0 = blockIdx.x * 128;
    int tid = threadIdx.x;

    __shared__ short Azh[2][128][40], Azl[2][128][40];   // 40,960 B total

    int wid = tid >> 6, lane = tid & 63;
    int wm = wid >> 2, wn = wid & 3;          // wave grid 2x4
    int lrow = lane & 15, lk = (lane >> 4) * 8;
    int srow = tid >> 2, squar = tid & 3;     // staging: row, 8-col quarter

    f32x4 acc[4][8];
#pragma unroll
    for (int m = 0; m < 4; ++m)
#pragma unroll
        for (int n = 0; n < 8; ++n) acc[m][n] = (f32x4){0.f, 0.f, 0.f, 0.f};

    float4 za, zb;
    const float* zrow = z + (size_t)(b0 + srow) * ZDIM + squar * 8;
    const short* bhbase = B1h + (size_t)(wn * 128 + lrow) * ZDIM + lk;
    const short* blbase = B1l + (size_t)(wn * 128 + lrow) * ZDIM + lk;

    // prologue: stage k0=0
    za = *reinterpret_cast<const float4*>(zrow);
    zb = *reinterpret_cast<const float4*>(zrow + 4);
    {
        s16x8 h, l;
#pragma unroll
        for (int j = 0; j < 4; ++j) { short hh, ll; split2((&za.x)[j], hh, ll); h[j] = hh; l[j] = ll; }
#pragma unroll
        for (int j = 0; j < 4; ++j) { short hh, ll; split2((&zb.x)[j], hh, ll); h[4+j] = hh; l[4+j] = ll; }
        *reinterpret_cast<s16x8*>(&Azh[0][srow][squar * 8]) = h;
        *reinterpret_cast<s16x8*>(&Azl[0][srow][squar * 8]) = l;
    }
    __syncthreads();

    for (int t = 0; t < 16; ++t) {
        int k0 = t * 32, cur = t & 1;
        if (t + 1 < 16) {                      // global z loads in flight over MFMAs
            za = *reinterpret_cast<const float4*>(zrow + (t + 1) * 32);
            zb = *reinterpret_cast<const float4*>(zrow + (t + 1) * 32 + 4);
        }
        s16x8 ah[4], al[4];
#pragma unroll
        for (int m = 0; m < 4; ++m) {
            ah[m] = *reinterpret_cast<const s16x8*>(&Azh[cur][wm * 64 + m * 16 + lrow][lk]);
            al[m] = *reinterpret_cast<const s16x8*>(&Azl[cur][wm * 64 + m * 16 + lrow][lk]);
        }
        s16x8 bh = *reinterpret_cast<const s16x8*>(bhbase + k0);
        s16x8 bl = *reinterpret_cast<const s16x8*>(blbase + k0);
#pragma unroll
        for (int n = 0; n < 8; ++n) {
            s16x8 nbh, nbl;
            if (n < 7) {
                nbh = *reinterpret_cast<const s16x8*>(bhbase + (size_t)(n + 1) * 16 * ZDIM + k0);
                nbl = *reinterpret_cast<const s16x8*>(blbase + (size_t)(n + 1) * 16 * ZDIM + k0);
            }
#pragma unroll
            for (int m = 0; m < 4; ++m) {
                acc[m][n] = __builtin_amdgcn_mfma_f32_16x16x32_bf16(ah[m], bh, acc[m][n], 0, 0, 0);
                acc[m][n] = __builtin_amdgcn_mfma_f32_16x16x32_bf16(al[m], bh, acc[m][n], 0, 0, 0);
                acc[m][n] = __builtin_amdgcn_mfma_f32_16x16x32_bf16(ah[m], bl, acc[m][n], 0, 0, 0);
            }
            bh = nbh; bl = nbl;
        }
        if (t + 1 < 16) {                      // split + write NEXT buffer
            s16x8 h, l;
#pragma unroll
            for (int j = 0; j < 4; ++j) { short hh, ll; split2((&za.x)[j], hh, ll); h[j] = hh; l[j] = ll; }
#pragma unroll
            for (int j = 0; j < 4; ++j) { short hh, ll; split2((&zb.x)[j], hh, ll); h[4+j] = hh; l[4+j] = ll; }
            *reinterpret_cast<s16x8*>(&Azh[cur ^ 1][srow][squar * 8]) = h;
            *reinterpret_cast<s16x8*>(&Azl[cur ^ 1][srow][squar * 8]) = l;
        }
        __syncthreads();
    }

    // epilogue: tanh, pack hB, ldj
    float cv[8], rr[8];
#pragma unroll
    for (int n = 0; n < 8; ++n) {
        int col = wn * 128 + n * 16 + lrow;
        cv[n] = cvec[col];
        rr[n] = rrii[col];
    }
    float lsum[4][4];
#pragma unroll
    for (int m = 0; m < 4; ++m)
#pragma unroll
        for (int r = 0; r < 4; ++r) lsum[m][r] = 0.0f;

#pragma unroll
    for (int m = 0; m < 4; ++m) {
#pragma unroll
        for (int r = 0; r < 4; ++r) {
            int b = b0 + wm * 64 + m * 16 + (lane >> 4) * 4 + r;
#pragma unroll
            for (int n = 0; n < 8; ++n) {
                float val = acc[m][n][r] + cv[n];
                float h = tanhf(val);
                short hh, ll;
                split2(h, hh, ll);
                int col = wn * 128 + n * 16 + lrow;
                hBp[(size_t)b * MDIM + col] = (uint32_t)(uint16_t)hh | ((uint32_t)(uint16_t)ll << 16);
                float der = 1.0f - h * h;
                lsum[m][r] += logf(fabsf(fmaf(der, rr[n], 1.0f)));
            }
        }
    }
#pragma unroll
    for (int m = 0; m < 4; ++m) {
#pragma unroll
        for (int r = 0; r < 4; ++r) {
            float s = lsum[m][r];
            s += __shfl_xor(s, 1, 64);
            s += __shfl_xor(s, 2, 64);
            s += __shfl_xor(s, 4, 64);
            s += __shfl_xor(s, 8, 64);
            if ((lane & 15) == 0)
                atomicAdd(&ldj[b0 + wm * 64 + m * 16 + (lane >> 4) * 4 + r], s);
        }
    }
}

// ---------------------------------------------------------------------------
// K5: gemm2 split-3 MFMA, IN-PLACE (block owns full 512-col rows of d_out).
// hB unpacked into double-buffered LDS; A fragments direct from L2.
// ---------------------------------------------------------------------------
__global__ void __launch_bounds__(512, 2) gemm2_mfma(const float* __restrict__ z,
                                                     const short* __restrict__ Ah_g,
                                                     const short* __restrict__ Al_g,
                                                     float* __restrict__ out) {
    int b0 = blockIdx.x * 128;
    int tid = threadIdx.x;
    const uint32_t* hBp = reinterpret_cast<const uint32_t*>(out);

    __shared__ short Hh[2][128][40], Hl[2][128][40];

    int wid = tid >> 6, lane = tid & 63;
    int wm = wid >> 2, wn = wid & 3;
    int lrow = lane & 15, lk = (lane >> 4) * 8;
    int srow = tid >> 2, squar = tid & 3;

    f32x4 acc[4][8];
#pragma unroll
    for (int m = 0; m < 4; ++m)
#pragma unroll
        for (int n = 0; n < 8; ++n) acc[m][n] = (f32x4){0.f, 0.f, 0.f, 0.f};

    uint4 ua, ub;
    const uint32_t* hrow = hBp + (size_t)(b0 + srow) * MDIM + squar * 8;
    const short* bhbase = Ah_g + (size_t)(wn * 128 + lrow) * MDIM + lk;
    const short* blbase = Al_g + (size_t)(wn * 128 + lrow) * MDIM + lk;

    ua = *reinterpret_cast<const uint4*>(hrow);
    ub = *reinterpret_cast<const uint4*>(hrow + 4);
    {
        s16x8 h, l;
        uint32_t uv[8] = {ua.x, ua.y, ua.z, ua.w, ub.x, ub.y, ub.z, ub.w};
#pragma unroll
        for (int j = 0; j < 8; ++j) { h[j] = (short)(uv[j] & 0xffffu); l[j] = (short)(uv[j] >> 16); }
        *reinterpret_cast<s16x8*>(&Hh[0][srow][squar * 8]) = h;
        *reinterpret_cast<s16x8*>(&Hl[0][srow][squar * 8]) = l;
    }
    __syncthreads();

    for (int t = 0; t < 16; ++t) {
        int m0 = t * 32, cur = t & 1;
        if (t + 1 < 16) {
            ua = *reinterpret_cast<const uint4*>(hrow + (t + 1) * 32);
            ub = *reinterpret_cast<const uint4*>(hrow + (t + 1) * 32 + 4);
        }
        s16x8 ah[4], al[4];
#pragma unroll
        for (int m = 0; m < 4; ++m) {
            ah[m] = *reinterpret_cast<const s16x8*>(&Hh[cur][wm * 64 + m * 16 + lrow][lk]);
            al[m] = *reinterpret_cast<const s16x8*>(&Hl[cur][wm * 64 + m * 16 + lrow][lk]);
        }
        s16x8 bh = *reinterpret_cast<const s16x8*>(bhbase + m0);
        s16x8 bl = *reinterpret_cast<const s16x8*>(blbase + m0);
#pragma unroll
        for (int n = 0; n < 8; ++n) {
            s16x8 nbh, nbl;
            if (n < 7) {
                nbh = *reinterpret_cast<const s16x8*>(bhbase + (size_t)(n + 1) * 16 * MDIM + m0);
                nbl = *reinterpret_cast<const s16x8*>(blbase + (size_t)(n + 1) * 16 * MDIM + m0);
            }
#pragma unroll
            for (int m = 0; m < 4; ++m) {
                acc[m][n] = __builtin_amdgcn_mfma_f32_16x16x32_bf16(ah[m], bh, acc[m][n], 0, 0, 0);
                acc[m][n] = __builtin_amdgcn_mfma_f32_16x16x32_bf16(al[m], bh, acc[m][n], 0, 0, 0);
                acc[m][n] = __builtin_amdgcn_mfma_f32_16x16x32_bf16(ah[m], bl, acc[m][n], 0, 0, 0);
            }
            bh = nbh; bl = nbl;
        }
        if (t + 1 < 16) {
            s16x8 h, l;
            uint32_t uv[8] = {ua.x, ua.y, ua.z, ua.w, ub.x, ub.y, ub.z, ub.w};
#pragma unroll
            for (int j = 0; j < 8; ++j) { h[j] = (short)(uv[j] & 0xffffu); l[j] = (short)(uv[j] >> 16); }
            *reinterpret_cast<s16x8*>(&Hh[cur ^ 1][srow][squar * 8]) = h;
            *reinterpret_cast<s16x8*>(&Hl[cur ^ 1][srow][squar * 8]) = l;
        }
        __syncthreads();
    }

    // epilogue: += z, write fp32 (overwrites packed hB; block owns these rows)
#pragma unroll
    for (int m = 0; m < 4; ++m) {
#pragma unroll
        for (int r = 0; r < 4; ++r) {
            int b = b0 + wm * 64 + m * 16 + (lane >> 4) * 4 + r;
#pragma unroll
            for (int n = 0; n < 8; ++n) {
                int colz = wn * 128 + n * 16 + lrow;
                out[(size_t)b * ZDIM + colz] = acc[m][n][r] + z[(size_t)b * ZDIM + colz];
            }
        }
    }
}

// ---------------------------------------------------------------------------
extern "C" void kernel_launch(void* const* d_in, const int* in_sizes, int n_in,
                              void* d_out, int out_size, void* d_ws, size_t ws_size,
                              hipStream_t stream) {
    const float* z      = (const float*)d_in[0];
    const float* v      = (const float*)d_in[1];
    const float* Rs     = (const float*)d_in[2];
    const float* r2diag = (const float*)d_in[3];
    const float* cvec   = (const float*)d_in[4];

    float* out = (float*)d_out;
    float* ldj = out + (size_t)NBATCH * ZDIM;

    float* ws   = (float*)d_ws;
    float* vn   = ws;                     // 511*512 f32
    float* Q    = ws + 262144;            // 512*512 f32
    float* rrii = ws + 524288;            // 512 f32
    short* sbase = (short*)(ws + 524800);
    short* Ah_g = sbase;                  // A hi, natural [z][m]
    short* Al_g = sbase + 262144;
    short* B1h  = sbase + 2 * 262144;     // B1 = Bt^T hi, [m][z]
    short* B1l  = sbase + 3 * 262144;

    hipMemsetAsync(ldj, 0, NBATCH * sizeof(float), stream);

    prep_kernel<<<512, 64, 0, stream>>>(v, Rs, r2diag, vn, rrii);
    householder_kernel<<<32, 256, 0, stream>>>(vn, Q);
    small_gemm_kernel<<<dim3(8, 8), 256, 0, stream>>>(Q, Rs, r2diag, Ah_g, Al_g, B1h, B1l);
    gemm1_mfma<<<512, 512, 0, stream>>>(z, B1h, B1l, cvec, rrii, (uint32_t*)out, ldj);
    gemm2_mfma<<<512, 512, 0, stream>>>(z, Ah_g, Al_g, out);
}